// Round 3
// baseline (681.642 us; speedup 1.0000x reference)
//
#include <hip/hip_runtime.h>
#include <cstdint>
#include <cstddef>

// Problem shape (fixed by the reference setup_inputs)
#define MDIM 8192
#define KDIM 2048
#define NDIM 2048
#define QBLK 128
#define KB   (KDIM / QBLK)   // 16
#define NB   (NDIM / QBLK)   // 16

typedef float floatx4 __attribute__((ext_vector_type(4)));
typedef int   int4v   __attribute__((ext_vector_type(4)));
typedef int   int8v   __attribute__((ext_vector_type(8)));

#define AS1 __attribute__((address_space(1)))
#define AS3 __attribute__((address_space(3)))

// ---------------------------------------------------------------------------
// fp8 e4m3fn helpers (software, bit-exact) — used by cold paths + check
// ---------------------------------------------------------------------------
__device__ inline float e4m3_rne(float q) {     // RNE to fp8 grid, |q| <= 448
    float aq = fabsf(q);
    float r;
    if (aq < 0.015625f) {                        // subnormal: grid 2^-9
        r = rintf(aq * 512.0f) * 0.001953125f;
    } else {
        unsigned u = __float_as_uint(aq);
        unsigned rem = u & 0xFFFFFu;
        unsigned base = u & ~0xFFFFFu;
        unsigned inc = (rem > 0x80000u || (rem == 0x80000u && (u & 0x100000u))) ? 0x100000u : 0u;
        r = __uint_as_float(base + inc);
    }
    return q < 0.0f ? -r : r;
}

__device__ inline unsigned e4m3_encode(float r) {  // r exactly on fp8 grid
    unsigned u = __float_as_uint(r);
    unsigned s = (u >> 24) & 0x80u;
    float a = fabsf(r);
    if (a < 0.015625f) return s | (unsigned)(a * 512.0f + 0.25f);
    unsigned e = ((u >> 23) & 0xFFu) - 120u;       // 1..15
    unsigned m = (u >> 20) & 7u;
    return s | (e << 3) | m;
}

__device__ inline float e4m3_decode(unsigned b) {
    unsigned s = b >> 7, e = (b >> 3) & 0xFu, m = b & 7u;
    float v;
    if (e == 0) v = (float)m * 0.001953125f;
    else        v = __uint_as_float((e + 120u) << 23) * (float)(8 + m) * 0.125f;
    return s ? -v : v;
}

__device__ inline int is_expbyte(unsigned b) {   // plausible f32/bf16 hi byte for fp8-exact value
    unsigned e = b & 0x7Fu;
    return (e >= 0x3Bu && e <= 0x43u) || e == 0x00u;
}

// ---------------------------------------------------------------------------
// Workspace layout
//   xq  [M][K]  fp8 bytes            @ 0        (16 MB)
//   wq8 [N][K]  fp8 bytes            @ 16 MB    (4 MB)
//   xs  [M][KB] f32 act scales       @ 20 MB    (512 KB)
//   flag int                         @ 20.5 MB
// ---------------------------------------------------------------------------
#define XQ_OFF  0
#define WQ_OFF  ((size_t)MDIM * KDIM)
#define XS_OFF  (WQ_OFF + (size_t)NDIM * KDIM)
#define FL_OFF  (XS_OFF + (size_t)MDIM * KB * 4)

#define QXB ((MDIM * KB) / 16)         // 8192 act-quant work items (16 qblocks each)
#define DWB ((NDIM * KDIM / 8) / 256)  // 2048 weight work items
#define PREP_GRID 2048                 // G11: cap blocks, grid-stride the rest

// ---------------------------------------------------------------------------
// Prep (grid-stride, 2048 blocks): act quant (8 elems/lane, 16 lanes per
// (1,128) block) -> fp8 bytes + scales via HW v_cvt_pk_fp8_f32 (bit-identical
// RNE from exact IEEE division); weight -> fp8 bytes (delivery format
// classified per wave via ballot).
// ---------------------------------------------------------------------------
__global__ __launch_bounds__(256) void prep_kernel(const float* __restrict__ x,
                                                   const void* __restrict__ wq,
                                                   unsigned char* __restrict__ xq,
                                                   unsigned char* __restrict__ wq8,
                                                   float* __restrict__ xs,
                                                   int* __restrict__ flag) {
    const int tid = threadIdx.x;
    if (blockIdx.x == 0 && tid == 0) *flag = 0;

    // ---- activation quant: one 16-lane group per (1,128) block ----
    const int g = tid >> 4;
    const int l = tid & 15;
    for (int blk = blockIdx.x; blk < QXB; blk += PREP_GRID) {
        const size_t bi = (size_t)blk * 16 + g;          // = m*KB + kb
        const size_t base = bi << 7;

        const float4* xp = (const float4*)(x + base + (size_t)l * 8);
        const float4 v0 = xp[0], v1 = xp[1];
        float a = fmaxf(fmaxf(fmaxf(fabsf(v0.x), fabsf(v0.y)), fmaxf(fabsf(v0.z), fabsf(v0.w))),
                        fmaxf(fmaxf(fabsf(v1.x), fabsf(v1.y)), fmaxf(fabsf(v1.z), fabsf(v1.w))));
        a = fmaxf(a, __shfl_xor(a, 1));
        a = fmaxf(a, __shfl_xor(a, 2));
        a = fmaxf(a, __shfl_xor(a, 4));
        a = fmaxf(a, __shfl_xor(a, 8));

        const float scale = fmaxf(a, 1e-12f) / 448.0f;
        if (l == 0) xs[bi] = scale;

        // exact IEEE divisions (same as reference), HW RNE pack to fp8
        const float q0 = v0.x / scale, q1 = v0.y / scale, q2 = v0.z / scale, q3 = v0.w / scale;
        const float q4 = v1.x / scale, q5 = v1.y / scale, q6 = v1.z / scale, q7 = v1.w / scale;
        int w0 = __builtin_amdgcn_cvt_pk_fp8_f32(q0, q1, 0, false);
        w0 = __builtin_amdgcn_cvt_pk_fp8_f32(q2, q3, w0, true);
        int w1 = __builtin_amdgcn_cvt_pk_fp8_f32(q4, q5, 0, false);
        w1 = __builtin_amdgcn_cvt_pk_fp8_f32(q6, q7, w1, true);
        *(uint2*)(xq + base + (size_t)l * 8) = make_uint2((unsigned)w0, (unsigned)w1);
    }

    // ---- weight repack to fp8 bytes (DWB == PREP_GRID: one iter/block) ----
    const int lane = tid & 63;
    const unsigned pw = ((const unsigned*)wq)[lane];
    const unsigned long long m3 = __ballot(is_expbyte((pw >> 24) & 0xFFu));
    const unsigned long long m1 = __ballot(((pw >> 8) & 0xFFu) == 0u);
    const int f = (__popcll(m3) >= 56) ? ((__popcll(m1) >= 56) ? 2 : 1) : 0;

    for (int blk = blockIdx.x; blk < DWB; blk += PREP_GRID) {
        const size_t idx = (size_t)blk * 256 + tid;
        const size_t off = idx * 8;

        unsigned lo, hi;
        if (f == 2) {              // float32 upcast delivery
            const float4* p = (const float4*)((const float*)wq + off);
            const float4 a = p[0], b = p[1];
            lo = e4m3_encode(a.x) | (e4m3_encode(a.y) << 8) | (e4m3_encode(a.z) << 16) | (e4m3_encode(a.w) << 24);
            hi = e4m3_encode(b.x) | (e4m3_encode(b.y) << 8) | (e4m3_encode(b.z) << 16) | (e4m3_encode(b.w) << 24);
        } else if (f == 1) {       // bf16 upcast delivery
            const ushort4 h0 = *(const ushort4*)((const unsigned short*)wq + off);
            const ushort4 h1 = *(((const ushort4*)((const unsigned short*)wq + off)) + 1);
            lo = e4m3_encode(__uint_as_float((unsigned)h0.x << 16))
               | (e4m3_encode(__uint_as_float((unsigned)h0.y << 16)) << 8)
               | (e4m3_encode(__uint_as_float((unsigned)h0.z << 16)) << 16)
               | (e4m3_encode(__uint_as_float((unsigned)h0.w << 16)) << 24);
            hi = e4m3_encode(__uint_as_float((unsigned)h1.x << 16))
               | (e4m3_encode(__uint_as_float((unsigned)h1.y << 16)) << 8)
               | (e4m3_encode(__uint_as_float((unsigned)h1.z << 16)) << 16)
               | (e4m3_encode(__uint_as_float((unsigned)h1.w << 16)) << 24);
        } else {                   // already raw fp8 bytes
            const uint2 d = *(const uint2*)((const unsigned char*)wq + off);
            lo = d.x; hi = d.y;
        }
        *(uint2*)(wq8 + off) = make_uint2(lo, hi);
    }
}

// ---------------------------------------------------------------------------
// Primary GEMM: 128x128 tile, 4 waves (2x2 of 64x64), MX fp8 K=128 per MFMA.
// m148-proven structure: double-buffered LDS, stage(t+1) issued BEFORE
// compute(t), ONE __syncthreads() per K-tile (its vmcnt(0) is the drain for
// our 8 in-flight loads, which had the whole 16-MFMA stretch to land).
// Writers always target buf^1 while readers read buf -> no intra-tile WAR;
// the single barrier orders the cross-tile handoff.  72.25 KB LDS ->
// 2 blocks/CU: independent blocks fill each other's stalls (the missing
// ingredient in rounds 1-2, which ran 1 lockstep block/CU).
// Staging / swizzle / FRAG / MFMA / epilogue bit-identical to the verified
// round-0 kernel.  Scales come from LDS (sxs transposed, swk) instead of
// per-tile uncoalesced global loads.
// ---------------------------------------------------------------------------
__global__ __launch_bounds__(256, 2) void gemm_mx_kernel(const unsigned char* __restrict__ Aq,
                                                         const unsigned char* __restrict__ Bq,
                                                         const float* __restrict__ xs,
                                                         const float* __restrict__ wsc,
                                                         float* __restrict__ C) {
    __shared__ unsigned char sA[2][128 * 128];   // 32 KB
    __shared__ unsigned char sB[2][128 * 128];   // 32 KB
    __shared__ float sxs[KB][128];               // 8 KB transposed act scales
    __shared__ float swk[KB];                    // weight scales for this n-tile

    const int tid  = threadIdx.x;
    const int wave = tid >> 6;
    const int lane = tid & 63;
    const int lrow = lane & 15;
    const int lk   = lane >> 4;          // k-group (32 bytes each)
    const int lk4  = lk * 4;
    const int wm   = (wave & 1) * 64;
    const int wn   = (wave >> 1) * 64;

    // XCD-grouped bijective tile map: 1024 blocks; XCD g gets m-tiles
    // [8g, 8g+8) x all 16 n-tiles (contiguous lid chunk of 128).
    const int bid = blockIdx.x;
    const int lid = ((bid & 7) << 7) | (bid >> 3);
    const int m0  = (lid >> 4) * 128;
    const int n0  = (lid & 15) * 128;
    const int nb  = n0 >> 7;

    // staging: thread t, pass it -> row = t/8 + it*32, physical chunk t&7
    // holding logical chunk (t&7)^(row&7); LDS dest linear at t*16 + it*4096.
    const int srow = tid >> 3;
    const int gck  = (tid & 7) ^ (srow & 7);
    const unsigned char* agp = Aq + (size_t)(m0 + srow) * KDIM + (size_t)gck * 16;
    const unsigned char* bgp = Bq + (size_t)(n0 + srow) * KDIM + (size_t)gck * 16;

#define GL(SRC, DST) __builtin_amdgcn_global_load_lds((const AS1 void*)(SRC), (AS3 void*)(DST), 16, 0, 0)
#define STAGE(buf, kb_) do {                                                          \
    const size_t koff_ = (size_t)(kb_) * QBLK;                                        \
    _Pragma("unroll")                                                                 \
    for (int it = 0; it < 4; ++it)                                                    \
        GL(agp + (size_t)(it * 32) * KDIM + koff_, &sA[buf][0] + tid * 16 + it * 4096); \
    _Pragma("unroll")                                                                 \
    for (int it = 0; it < 4; ++it)                                                    \
        GL(bgp + (size_t)(it * 32) * KDIM + koff_, &sB[buf][0] + tid * 16 + it * 4096); \
} while (0)

    // prologue: stage tile 0 + scale tables, then full drain
    STAGE(0, 0);
    if (tid < 128) {
        const float4* xp = (const float4*)(xs + (size_t)(m0 + tid) * KB);
#pragma unroll
        for (int q = 0; q < 4; ++q) {
            const float4 v = xp[q];
            sxs[q * 4 + 0][tid] = v.x;
            sxs[q * 4 + 1][tid] = v.y;
            sxs[q * 4 + 2][tid] = v.z;
            sxs[q * 4 + 3][tid] = v.w;
        }
    }
    if (tid < KB) swk[tid] = wsc[nb * KB + tid];
    __syncthreads();

    floatx4 acc[4][4] = {};
    const floatx4 zero = {0.f, 0.f, 0.f, 0.f};

#define FRAG(dst, basep, ROW) do {                                              \
    const int _r = (ROW);                                                       \
    const unsigned char* _p = (basep) + _r * 128;                               \
    const int _c0 = (lk * 2) ^ (_r & 7);                                        \
    ((int4v*)&(dst))[0] = *(const int4v*)(_p + _c0 * 16);                       \
    ((int4v*)&(dst))[1] = *(const int4v*)(_p + (_c0 ^ 1) * 16);                 \
} while (0)

    for (int t = 0; t < KB; ++t) {
        const int cur = t & 1;
        const unsigned char* sAc = &sA[cur][0];
        const unsigned char* sBc = &sB[cur][0];

        if (t + 1 < KB) STAGE(cur ^ 1, t + 1);   // issue next-tile loads FIRST

        int8v af[4], bf[4];
#pragma unroll
        for (int i = 0; i < 4; ++i) {
            FRAG(af[i], sAc, wm + i * 16 + lrow);
            FRAG(bf[i], sBc, wn + i * 16 + lrow);
        }

        const float wsk = swk[t];
        floatx4 cs[4];
#pragma unroll
        for (int i = 0; i < 4; ++i)
            cs[i] = (*(const floatx4*)&sxs[t][wm + i * 16 + lk4]) * wsk;

#pragma unroll
        for (int i = 0; i < 4; ++i)
#pragma unroll
            for (int j = 0; j < 4; ++j) {
                floatx4 blk = __builtin_amdgcn_mfma_scale_f32_16x16x128_f8f6f4(
                    af[i], bf[j], zero, 0, 0, 0, 0x7F7F7F7F, 0, 0x7F7F7F7F);
                acc[i][j] += cs[i] * blk;
            }

        __syncthreads();   // vmcnt(0)+lgkmcnt(0): staged tile landed everywhere
    }
#undef FRAG
#undef STAGE
#undef GL

    // Epilogue: col = lane&15, row = lk*4 + r
#pragma unroll
    for (int i = 0; i < 4; ++i) {
        const int row0 = m0 + wm + i * 16 + lk4;
#pragma unroll
        for (int r = 0; r < 4; ++r) {
            float* cp = C + (size_t)(row0 + r) * NDIM + n0 + wn + lrow;
#pragma unroll
            for (int j = 0; j < 4; ++j)
                cp[j * 16] = acc[i][j][r];
        }
    }
}

// ---------------------------------------------------------------------------
// Check: recompute 64 sampled outputs exactly from the quantized bytes; set
// flag if the MX GEMM result deviates (NaN-safe compare).
// ---------------------------------------------------------------------------
__global__ __launch_bounds__(256) void check_kernel(const unsigned char* __restrict__ xq,
                                                    const unsigned char* __restrict__ wq8,
                                                    const float* __restrict__ xs,
                                                    const float* __restrict__ wsc,
                                                    const float* __restrict__ y,
                                                    int* __restrict__ flag) {
    const int s = blockIdx.x;
    const int m = (s * 1237 + 11) & (MDIM - 1);
    const int n = (s * 389 + 7) & (NDIM - 1);
    const int tid = threadIdx.x;
    const int k0 = tid * 8;
    const int kb = k0 >> 7;

    const unsigned char* xp = xq + (size_t)m * KDIM + k0;
    const unsigned char* wp = wq8 + (size_t)n * KDIM + k0;
    float dot = 0.f;
#pragma unroll
    for (int i = 0; i < 8; ++i)
        dot += e4m3_decode(xp[i]) * e4m3_decode(wp[i]);
    float part = dot * xs[m * KB + kb] * wsc[(n >> 7) * KB + kb];

#pragma unroll
    for (int o = 32; o > 0; o >>= 1) part += __shfl_down(part, o);
    __shared__ float wsum[4];
    if ((tid & 63) == 0) wsum[tid >> 6] = part;
    __syncthreads();
    if (tid == 0) {
        const float tot = wsum[0] + wsum[1] + wsum[2] + wsum[3];
        const float d = tot - y[(size_t)m * NDIM + n];
        if (!(fabsf(d) <= 0.05f)) atomicOr(flag, 1);
    }
}

// ---------------------------------------------------------------------------
// Fallback GEMM (flag-guarded): non-scaled mfma_f32_16x16x32_fp8_fp8 (m145-
// verified k-geometry) + identical VALU scale fixup. Only runs if the MX
// layout check failed. Unchanged from the verified kernel.
// ---------------------------------------------------------------------------
__global__ __launch_bounds__(256, 2) void gemm_fb_kernel(const unsigned char* __restrict__ Aq,
                                                         const unsigned char* __restrict__ Bq,
                                                         const float* __restrict__ xs,
                                                         const float* __restrict__ wsc,
                                                         float* __restrict__ C,
                                                         const int* __restrict__ flag) {
    if (*flag == 0) return;

    __shared__ unsigned char sA[128 * 128];
    __shared__ unsigned char sB[128 * 128];

    const int tid  = threadIdx.x;
    const int wave = tid >> 6;
    const int lane = tid & 63;
    const int lrow = lane & 15;
    const int lk   = lane >> 4;
    const int wm   = (wave & 1) * 64;
    const int wn   = (wave >> 1) * 64;
    const int m0   = blockIdx.y * 128;
    const int n0   = blockIdx.x * 128;
    const int nb   = n0 >> 7;

    const int srow = tid >> 3;
    const int gck  = (tid & 7) ^ (srow & 7);
    const unsigned char* agp = Aq + (size_t)(m0 + srow) * KDIM + gck * 16;
    const unsigned char* bgp = Bq + (size_t)(n0 + srow) * KDIM + gck * 16;

    floatx4 acc[4][4] = {};

    for (int kb = 0; kb < KB; ++kb) {
        const size_t koff = (size_t)kb * QBLK;
        __syncthreads();
#pragma unroll
        for (int it = 0; it < 4; ++it)
            __builtin_amdgcn_global_load_lds(
                (const AS1 void*)(agp + (size_t)(it * 32) * KDIM + koff),
                (AS3 void*)(sA + tid * 16 + it * 4096), 16, 0, 0);
#pragma unroll
        for (int it = 0; it < 4; ++it)
            __builtin_amdgcn_global_load_lds(
                (const AS1 void*)(bgp + (size_t)(it * 32) * KDIM + koff),
                (AS3 void*)(sB + tid * 16 + it * 4096), 16, 0, 0);
        __syncthreads();

        floatx4 blk[4][4] = {};
#pragma unroll
        for (int ks = 0; ks < 4; ++ks) {        // K = 32 per MFMA
            long a8[4], b8[4];
            const int lc = ks * 2 + (lk >> 1);  // logical chunk of this 8B frag
            const int bo = (lk & 1) * 8;        // byte offset within chunk
#pragma unroll
            for (int i = 0; i < 4; ++i) {
                const int Ra = wm + i * 16 + lrow;
                a8[i] = *(const long*)(sA + Ra * 128 + (lc ^ (Ra & 7)) * 16 + bo);
                const int Rb = wn + i * 16 + lrow;
                b8[i] = *(const long*)(sB + Rb * 128 + (lc ^ (Rb & 7)) * 16 + bo);
            }
#pragma unroll
            for (int i = 0; i < 4; ++i)
#pragma unroll
                for (int j = 0; j < 4; ++j)
                    blk[i][j] = __builtin_amdgcn_mfma_f32_16x16x32_fp8_fp8(a8[i], b8[j], blk[i][j], 0, 0, 0);
        }

        const float wsk = wsc[nb * KB + kb];
#pragma unroll
        for (int i = 0; i < 4; ++i) {
            float cs[4];
#pragma unroll
            for (int r = 0; r < 4; ++r)
                cs[r] = xs[(size_t)(m0 + wm + i * 16 + lk * 4 + r) * KB + kb] * wsk;
#pragma unroll
            for (int j = 0; j < 4; ++j)
#pragma unroll
                for (int r = 0; r < 4; ++r)
                    acc[i][j][r] += cs[r] * blk[i][j][r];
        }
    }

#pragma unroll
    for (int i = 0; i < 4; ++i) {
        const int row0 = m0 + wm + i * 16 + lk * 4;
#pragma unroll
        for (int r = 0; r < 4; ++r) {
            float* cp = C + (size_t)(row0 + r) * NDIM + n0 + wn + lrow;
#pragma unroll
            for (int j = 0; j < 4; ++j)
                cp[j * 16] = acc[i][j][r];
        }
    }
}

// ---------------------------------------------------------------------------
extern "C" void kernel_launch(void* const* d_in, const int* in_sizes, int n_in,
                              void* d_out, int out_size, void* d_ws, size_t ws_size,
                              hipStream_t stream) {
    const float* x      = (const float*)d_in[0];
    const void* wq      = d_in[1];
    const float* wscale = (const float*)d_in[2];
    float* y            = (float*)d_out;

    unsigned char* xq  = (unsigned char*)d_ws + XQ_OFF;
    unsigned char* wq8 = (unsigned char*)d_ws + WQ_OFF;
    float* xs          = (float*)((unsigned char*)d_ws + XS_OFF);
    int* flag          = (int*)((unsigned char*)d_ws + FL_OFF);

    prep_kernel<<<PREP_GRID, 256, 0, stream>>>(x, wq, xq, wq8, xs, flag);
    gemm_mx_kernel<<<(MDIM / 128) * (NDIM / 128), 256, 0, stream>>>(xq, wq8, xs, wscale, y);
    check_kernel<<<64, 256, 0, stream>>>(xq, wq8, xs, wscale, y, flag);
    gemm_fb_kernel<<<dim3(NDIM / 128, MDIM / 128), 256, 0, stream>>>(xq, wq8, xs, wscale, y, flag);
}

// Round 4
// 678.460 us; speedup vs baseline: 1.0047x; 1.0047x over previous
//
#include <hip/hip_runtime.h>
#include <cstdint>
#include <cstddef>

// Problem shape (fixed by the reference setup_inputs)
#define MDIM 8192
#define KDIM 2048
#define NDIM 2048
#define QBLK 128
#define KB   (KDIM / QBLK)   // 16
#define NB   (NDIM / QBLK)   // 16

typedef float floatx4 __attribute__((ext_vector_type(4)));
typedef int   int4v   __attribute__((ext_vector_type(4)));
typedef int   int8v   __attribute__((ext_vector_type(8)));

#define AS1 __attribute__((address_space(1)))
#define AS3 __attribute__((address_space(3)))

// ---------------------------------------------------------------------------
// fp8 e4m3fn helpers (software, bit-exact) — used by cold paths + check
// ---------------------------------------------------------------------------
__device__ inline float e4m3_rne(float q) {     // RNE to fp8 grid, |q| <= 448
    float aq = fabsf(q);
    float r;
    if (aq < 0.015625f) {                        // subnormal: grid 2^-9
        r = rintf(aq * 512.0f) * 0.001953125f;
    } else {
        unsigned u = __float_as_uint(aq);
        unsigned rem = u & 0xFFFFFu;
        unsigned base = u & ~0xFFFFFu;
        unsigned inc = (rem > 0x80000u || (rem == 0x80000u && (u & 0x100000u))) ? 0x100000u : 0u;
        r = __uint_as_float(base + inc);
    }
    return q < 0.0f ? -r : r;
}

__device__ inline unsigned e4m3_encode(float r) {  // r exactly on fp8 grid
    unsigned u = __float_as_uint(r);
    unsigned s = (u >> 24) & 0x80u;
    float a = fabsf(r);
    if (a < 0.015625f) return s | (unsigned)(a * 512.0f + 0.25f);
    unsigned e = ((u >> 23) & 0xFFu) - 120u;       // 1..15
    unsigned m = (u >> 20) & 7u;
    return s | (e << 3) | m;
}

__device__ inline float e4m3_decode(unsigned b) {
    unsigned s = b >> 7, e = (b >> 3) & 0xFu, m = b & 7u;
    float v;
    if (e == 0) v = (float)m * 0.001953125f;
    else        v = __uint_as_float((e + 120u) << 23) * (float)(8 + m) * 0.125f;
    return s ? -v : v;
}

__device__ inline int is_expbyte(unsigned b) {   // plausible f32/bf16 hi byte for fp8-exact value
    unsigned e = b & 0x7Fu;
    return (e >= 0x3Bu && e <= 0x43u) || e == 0x00u;
}

// ---------------------------------------------------------------------------
// Workspace layout
//   xq  [M][K]  fp8 bytes            @ 0        (16 MB)
//   wq8 [N][K]  fp8 bytes            @ 16 MB    (4 MB)
//   xs  [M][KB] f32 act scales       @ 20 MB    (512 KB)
//   flag int                         @ 20.5 MB
// ---------------------------------------------------------------------------
#define XQ_OFF  0
#define WQ_OFF  ((size_t)MDIM * KDIM)
#define XS_OFF  (WQ_OFF + (size_t)NDIM * KDIM)
#define FL_OFF  (XS_OFF + (size_t)MDIM * KB * 4)

#define QXB ((MDIM * KB) / 16)         // 8192 act-quant work items (16 qblocks each)
#define DWB ((NDIM * KDIM / 8) / 256)  // 2048 weight work items
#define PREP_GRID 2048                 // G11: cap blocks, grid-stride the rest

// ---------------------------------------------------------------------------
// Prep (grid-stride, 2048 blocks): act quant (8 elems/lane, 16 lanes per
// (1,128) block) -> fp8 bytes + scales via HW v_cvt_pk_fp8_f32 (bit-identical
// RNE from exact IEEE division); weight -> fp8 bytes (delivery format
// classified per wave via ballot).
// ---------------------------------------------------------------------------
__global__ __launch_bounds__(256) void prep_kernel(const float* __restrict__ x,
                                                   const void* __restrict__ wq,
                                                   unsigned char* __restrict__ xq,
                                                   unsigned char* __restrict__ wq8,
                                                   float* __restrict__ xs,
                                                   int* __restrict__ flag) {
    const int tid = threadIdx.x;
    if (blockIdx.x == 0 && tid == 0) *flag = 0;

    // ---- activation quant: one 16-lane group per (1,128) block ----
    const int g = tid >> 4;
    const int l = tid & 15;
    for (int blk = blockIdx.x; blk < QXB; blk += PREP_GRID) {
        const size_t bi = (size_t)blk * 16 + g;          // = m*KB + kb
        const size_t base = bi << 7;

        const float4* xp = (const float4*)(x + base + (size_t)l * 8);
        const float4 v0 = xp[0], v1 = xp[1];
        float a = fmaxf(fmaxf(fmaxf(fabsf(v0.x), fabsf(v0.y)), fmaxf(fabsf(v0.z), fabsf(v0.w))),
                        fmaxf(fmaxf(fabsf(v1.x), fabsf(v1.y)), fmaxf(fabsf(v1.z), fabsf(v1.w))));
        a = fmaxf(a, __shfl_xor(a, 1));
        a = fmaxf(a, __shfl_xor(a, 2));
        a = fmaxf(a, __shfl_xor(a, 4));
        a = fmaxf(a, __shfl_xor(a, 8));

        const float scale = fmaxf(a, 1e-12f) / 448.0f;
        if (l == 0) xs[bi] = scale;

        // exact IEEE divisions (same as reference), HW RNE pack to fp8
        const float q0 = v0.x / scale, q1 = v0.y / scale, q2 = v0.z / scale, q3 = v0.w / scale;
        const float q4 = v1.x / scale, q5 = v1.y / scale, q6 = v1.z / scale, q7 = v1.w / scale;
        int w0 = __builtin_amdgcn_cvt_pk_fp8_f32(q0, q1, 0, false);
        w0 = __builtin_amdgcn_cvt_pk_fp8_f32(q2, q3, w0, true);
        int w1 = __builtin_amdgcn_cvt_pk_fp8_f32(q4, q5, 0, false);
        w1 = __builtin_amdgcn_cvt_pk_fp8_f32(q6, q7, w1, true);
        *(uint2*)(xq + base + (size_t)l * 8) = make_uint2((unsigned)w0, (unsigned)w1);
    }

    // ---- weight repack to fp8 bytes (DWB == PREP_GRID: one iter/block) ----
    const int lane = tid & 63;
    const unsigned pw = ((const unsigned*)wq)[lane];
    const unsigned long long m3 = __ballot(is_expbyte((pw >> 24) & 0xFFu));
    const unsigned long long m1 = __ballot(((pw >> 8) & 0xFFu) == 0u);
    const int f = (__popcll(m3) >= 56) ? ((__popcll(m1) >= 56) ? 2 : 1) : 0;

    for (int blk = blockIdx.x; blk < DWB; blk += PREP_GRID) {
        const size_t idx = (size_t)blk * 256 + tid;
        const size_t off = idx * 8;

        unsigned lo, hi;
        if (f == 2) {              // float32 upcast delivery
            const float4* p = (const float4*)((const float*)wq + off);
            const float4 a = p[0], b = p[1];
            lo = e4m3_encode(a.x) | (e4m3_encode(a.y) << 8) | (e4m3_encode(a.z) << 16) | (e4m3_encode(a.w) << 24);
            hi = e4m3_encode(b.x) | (e4m3_encode(b.y) << 8) | (e4m3_encode(b.z) << 16) | (e4m3_encode(b.w) << 24);
        } else if (f == 1) {       // bf16 upcast delivery
            const ushort4 h0 = *(const ushort4*)((const unsigned short*)wq + off);
            const ushort4 h1 = *(((const ushort4*)((const unsigned short*)wq + off)) + 1);
            lo = e4m3_encode(__uint_as_float((unsigned)h0.x << 16))
               | (e4m3_encode(__uint_as_float((unsigned)h0.y << 16)) << 8)
               | (e4m3_encode(__uint_as_float((unsigned)h0.z << 16)) << 16)
               | (e4m3_encode(__uint_as_float((unsigned)h0.w << 16)) << 24);
            hi = e4m3_encode(__uint_as_float((unsigned)h1.x << 16))
               | (e4m3_encode(__uint_as_float((unsigned)h1.y << 16)) << 8)
               | (e4m3_encode(__uint_as_float((unsigned)h1.z << 16)) << 16)
               | (e4m3_encode(__uint_as_float((unsigned)h1.w << 16)) << 24);
        } else {                   // already raw fp8 bytes
            const uint2 d = *(const uint2*)((const unsigned char*)wq + off);
            lo = d.x; hi = d.y;
        }
        *(uint2*)(wq8 + off) = make_uint2(lo, hi);
    }
}

// ---------------------------------------------------------------------------
// Primary GEMM: 128x128 tile, 4 waves (2x2 of 64x64), MX fp8 K=128 per MFMA.
// Double-buffered LDS, stage(t+1) issued BEFORE compute(t), ONE
// __syncthreads() per K-tile. Writers always target buf^1 while readers read
// buf -> no intra-tile WAR; the barrier orders the cross-tile handoff.
// 72.25 KB LDS -> 2 blocks/CU so independent blocks fill each other's stalls.
// FRAG uses __builtin_shufflevector ONLY (round-0 form): the round-3
// address-taking form (((int4v*)&dst)[0]=..., into array elements) forced
// af[]/bf[] to scratch -> 1.07 GB of spill traffic and a 10x regression.
// Scales come from LDS (sxs transposed, swk).
// ---------------------------------------------------------------------------
__global__ __launch_bounds__(256, 2) void gemm_mx_kernel(const unsigned char* __restrict__ Aq,
                                                         const unsigned char* __restrict__ Bq,
                                                         const float* __restrict__ xs,
                                                         const float* __restrict__ wsc,
                                                         float* __restrict__ C) {
    __shared__ unsigned char sA[2][128 * 128];   // 32 KB
    __shared__ unsigned char sB[2][128 * 128];   // 32 KB
    __shared__ float sxs[KB][128];               // 8 KB transposed act scales
    __shared__ float swk[KB];                    // weight scales for this n-tile

    const int tid  = threadIdx.x;
    const int wave = tid >> 6;
    const int lane = tid & 63;
    const int lrow = lane & 15;
    const int lk   = lane >> 4;          // k-group (32 bytes each)
    const int lk4  = lk * 4;
    const int wm   = (wave & 1) * 64;
    const int wn   = (wave >> 1) * 64;

    // XCD-grouped bijective tile map: 1024 blocks; XCD g gets m-tiles
    // [8g, 8g+8) x all 16 n-tiles (contiguous lid chunk of 128).
    const int bid = blockIdx.x;
    const int lid = ((bid & 7) << 7) | (bid >> 3);
    const int m0  = (lid >> 4) * 128;
    const int n0  = (lid & 15) * 128;
    const int nb  = n0 >> 7;

    // staging: thread t, pass it -> row = t/8 + it*32, physical chunk t&7
    // holding logical chunk (t&7)^(row&7); LDS dest linear at t*16 + it*4096.
    const int srow = tid >> 3;
    const int gck  = (tid & 7) ^ (srow & 7);
    const unsigned char* agp = Aq + (size_t)(m0 + srow) * KDIM + (size_t)gck * 16;
    const unsigned char* bgp = Bq + (size_t)(n0 + srow) * KDIM + (size_t)gck * 16;

#define GL(SRC, DST) __builtin_amdgcn_global_load_lds((const AS1 void*)(SRC), (AS3 void*)(DST), 16, 0, 0)
#define STAGE(buf, kb_) do {                                                          \
    const size_t koff_ = (size_t)(kb_) * QBLK;                                        \
    _Pragma("unroll")                                                                 \
    for (int it = 0; it < 4; ++it)                                                    \
        GL(agp + (size_t)(it * 32) * KDIM + koff_, &sA[buf][0] + tid * 16 + it * 4096); \
    _Pragma("unroll")                                                                 \
    for (int it = 0; it < 4; ++it)                                                    \
        GL(bgp + (size_t)(it * 32) * KDIM + koff_, &sB[buf][0] + tid * 16 + it * 4096); \
} while (0)

    // prologue: stage tile 0 + scale tables, then full drain
    STAGE(0, 0);
    if (tid < 128) {
        const float4* xp = (const float4*)(xs + (size_t)(m0 + tid) * KB);
#pragma unroll
        for (int q = 0; q < 4; ++q) {
            const float4 v = xp[q];
            sxs[q * 4 + 0][tid] = v.x;
            sxs[q * 4 + 1][tid] = v.y;
            sxs[q * 4 + 2][tid] = v.z;
            sxs[q * 4 + 3][tid] = v.w;
        }
    }
    if (tid < KB) swk[tid] = wsc[nb * KB + tid];
    __syncthreads();

    floatx4 acc[4][4] = {};
    const floatx4 zero = {0.f, 0.f, 0.f, 0.f};

    for (int t = 0; t < KB; ++t) {
        const int cur = t & 1;
        const unsigned char* sAc = &sA[cur][0];
        const unsigned char* sBc = &sB[cur][0];

        if (t + 1 < KB) STAGE(cur ^ 1, t + 1);   // issue next-tile loads FIRST

        // fragments: logical bytes [lk*32, lk*32+32) of each row — SSA only,
        // no address-taking (scratch-spill hazard, see round-3 post-mortem)
        int8v af[4], bf[4];
#pragma unroll
        for (int i = 0; i < 4; ++i) {
            const int Ra = wm + i * 16 + lrow;
            const int c0 = (lk * 2) ^ (Ra & 7);
            int4v alo = *(const int4v*)(sAc + Ra * 128 + c0 * 16);
            int4v ahi = *(const int4v*)(sAc + Ra * 128 + (c0 ^ 1) * 16);
            af[i] = __builtin_shufflevector(alo, ahi, 0, 1, 2, 3, 4, 5, 6, 7);
            const int Rb = wn + i * 16 + lrow;
            const int d0 = (lk * 2) ^ (Rb & 7);
            int4v blo = *(const int4v*)(sBc + Rb * 128 + d0 * 16);
            int4v bhi = *(const int4v*)(sBc + Rb * 128 + (d0 ^ 1) * 16);
            bf[i] = __builtin_shufflevector(blo, bhi, 0, 1, 2, 3, 4, 5, 6, 7);
        }

        const float wsk = swk[t];
        floatx4 cs[4];
#pragma unroll
        for (int i = 0; i < 4; ++i)
            cs[i] = (*(const floatx4*)&sxs[t][wm + i * 16 + lk4]) * wsk;

#pragma unroll
        for (int i = 0; i < 4; ++i)
#pragma unroll
            for (int j = 0; j < 4; ++j) {
                floatx4 blk = __builtin_amdgcn_mfma_scale_f32_16x16x128_f8f6f4(
                    af[i], bf[j], zero, 0, 0, 0, 0x7F7F7F7F, 0, 0x7F7F7F7F);
                acc[i][j] += cs[i] * blk;
            }

        __syncthreads();   // vmcnt(0)+lgkmcnt(0): staged tile landed everywhere
    }
#undef STAGE
#undef GL

    // Epilogue: col = lane&15, row = lk*4 + r
#pragma unroll
    for (int i = 0; i < 4; ++i) {
        const int row0 = m0 + wm + i * 16 + lk4;
#pragma unroll
        for (int r = 0; r < 4; ++r) {
            float* cp = C + (size_t)(row0 + r) * NDIM + n0 + wn + lrow;
#pragma unroll
            for (int j = 0; j < 4; ++j)
                cp[j * 16] = acc[i][j][r];
        }
    }
}

// ---------------------------------------------------------------------------
// Check: recompute 64 sampled outputs exactly from the quantized bytes; set
// flag if the MX GEMM result deviates (NaN-safe compare).
// ---------------------------------------------------------------------------
__global__ __launch_bounds__(256) void check_kernel(const unsigned char* __restrict__ xq,
                                                    const unsigned char* __restrict__ wq8,
                                                    const float* __restrict__ xs,
                                                    const float* __restrict__ wsc,
                                                    const float* __restrict__ y,
                                                    int* __restrict__ flag) {
    const int s = blockIdx.x;
    const int m = (s * 1237 + 11) & (MDIM - 1);
    const int n = (s * 389 + 7) & (NDIM - 1);
    const int tid = threadIdx.x;
    const int k0 = tid * 8;
    const int kb = k0 >> 7;

    const unsigned char* xp = xq + (size_t)m * KDIM + k0;
    const unsigned char* wp = wq8 + (size_t)n * KDIM + k0;
    float dot = 0.f;
#pragma unroll
    for (int i = 0; i < 8; ++i)
        dot += e4m3_decode(xp[i]) * e4m3_decode(wp[i]);
    float part = dot * xs[m * KB + kb] * wsc[(n >> 7) * KB + kb];

#pragma unroll
    for (int o = 32; o > 0; o >>= 1) part += __shfl_down(part, o);
    __shared__ float wsum[4];
    if ((tid & 63) == 0) wsum[tid >> 6] = part;
    __syncthreads();
    if (tid == 0) {
        const float tot = wsum[0] + wsum[1] + wsum[2] + wsum[3];
        const float d = tot - y[(size_t)m * NDIM + n];
        if (!(fabsf(d) <= 0.05f)) atomicOr(flag, 1);
    }
}

// ---------------------------------------------------------------------------
// Fallback GEMM (flag-guarded): non-scaled mfma_f32_16x16x32_fp8_fp8 (m145-
// verified k-geometry) + identical VALU scale fixup. Only runs if the MX
// layout check failed. Unchanged from the verified kernel.
// ---------------------------------------------------------------------------
__global__ __launch_bounds__(256, 2) void gemm_fb_kernel(const unsigned char* __restrict__ Aq,
                                                         const unsigned char* __restrict__ Bq,
                                                         const float* __restrict__ xs,
                                                         const float* __restrict__ wsc,
                                                         float* __restrict__ C,
                                                         const int* __restrict__ flag) {
    if (*flag == 0) return;

    __shared__ unsigned char sA[128 * 128];
    __shared__ unsigned char sB[128 * 128];

    const int tid  = threadIdx.x;
    const int wave = tid >> 6;
    const int lane = tid & 63;
    const int lrow = lane & 15;
    const int lk   = lane >> 4;
    const int wm   = (wave & 1) * 64;
    const int wn   = (wave >> 1) * 64;
    const int m0   = blockIdx.y * 128;
    const int n0   = blockIdx.x * 128;
    const int nb   = n0 >> 7;

    const int srow = tid >> 3;
    const int gck  = (tid & 7) ^ (srow & 7);
    const unsigned char* agp = Aq + (size_t)(m0 + srow) * KDIM + gck * 16;
    const unsigned char* bgp = Bq + (size_t)(n0 + srow) * KDIM + gck * 16;

    floatx4 acc[4][4] = {};

    for (int kb = 0; kb < KB; ++kb) {
        const size_t koff = (size_t)kb * QBLK;
        __syncthreads();
#pragma unroll
        for (int it = 0; it < 4; ++it)
            __builtin_amdgcn_global_load_lds(
                (const AS1 void*)(agp + (size_t)(it * 32) * KDIM + koff),
                (AS3 void*)(sA + tid * 16 + it * 4096), 16, 0, 0);
#pragma unroll
        for (int it = 0; it < 4; ++it)
            __builtin_amdgcn_global_load_lds(
                (const AS1 void*)(bgp + (size_t)(it * 32) * KDIM + koff),
                (AS3 void*)(sB + tid * 16 + it * 4096), 16, 0, 0);
        __syncthreads();

        floatx4 blk[4][4] = {};
#pragma unroll
        for (int ks = 0; ks < 4; ++ks) {        // K = 32 per MFMA
            long a8[4], b8[4];
            const int lc = ks * 2 + (lk >> 1);  // logical chunk of this 8B frag
            const int bo = (lk & 1) * 8;        // byte offset within chunk
#pragma unroll
            for (int i = 0; i < 4; ++i) {
                const int Ra = wm + i * 16 + lrow;
                a8[i] = *(const long*)(sA + Ra * 128 + (lc ^ (Ra & 7)) * 16 + bo);
                const int Rb = wn + i * 16 + lrow;
                b8[i] = *(const long*)(sB + Rb * 128 + (lc ^ (Rb & 7)) * 16 + bo);
            }
#pragma unroll
            for (int i = 0; i < 4; ++i)
#pragma unroll
                for (int j = 0; j < 4; ++j)
                    blk[i][j] = __builtin_amdgcn_mfma_f32_16x16x32_fp8_fp8(a8[i], b8[j], blk[i][j], 0, 0, 0);
        }

        const float wsk = wsc[nb * KB + kb];
#pragma unroll
        for (int i = 0; i < 4; ++i) {
            float cs[4];
#pragma unroll
            for (int r = 0; r < 4; ++r)
                cs[r] = xs[(size_t)(m0 + wm + i * 16 + lk * 4 + r) * KB + kb] * wsk;
#pragma unroll
            for (int j = 0; j < 4; ++j)
#pragma unroll
                for (int r = 0; r < 4; ++r)
                    acc[i][j][r] += cs[r] * blk[i][j][r];
        }
    }

#pragma unroll
    for (int i = 0; i < 4; ++i) {
        const int row0 = m0 + wm + i * 16 + lk * 4;
#pragma unroll
        for (int r = 0; r < 4; ++r) {
            float* cp = C + (size_t)(row0 + r) * NDIM + n0 + wn + lrow;
#pragma unroll
            for (int j = 0; j < 4; ++j)
                cp[j * 16] = acc[i][j][r];
        }
    }
}

// ---------------------------------------------------------------------------
extern "C" void kernel_launch(void* const* d_in, const int* in_sizes, int n_in,
                              void* d_out, int out_size, void* d_ws, size_t ws_size,
                              hipStream_t stream) {
    const float* x      = (const float*)d_in[0];
    const void* wq      = d_in[1];
    const float* wscale = (const float*)d_in[2];
    float* y            = (float*)d_out;

    unsigned char* xq  = (unsigned char*)d_ws + XQ_OFF;
    unsigned char* wq8 = (unsigned char*)d_ws + WQ_OFF;
    float* xs          = (float*)((unsigned char*)d_ws + XS_OFF);
    int* flag          = (int*)((unsigned char*)d_ws + FL_OFF);

    prep_kernel<<<PREP_GRID, 256, 0, stream>>>(x, wq, xq, wq8, xs, flag);
    gemm_mx_kernel<<<(MDIM / 128) * (NDIM / 128), 256, 0, stream>>>(xq, wq8, xs, wscale, y);
    check_kernel<<<64, 256, 0, stream>>>(xq, wq8, xs, wscale, y, flag);
    gemm_fb_kernel<<<dim3(NDIM / 128, MDIM / 128), 256, 0, stream>>>(xq, wq8, xs, wscale, y, flag);
}

// Round 5
// 181.714 us; speedup vs baseline: 3.7512x; 3.7337x over previous
//
#include <hip/hip_runtime.h>
#include <cstdint>
#include <cstddef>

// Problem shape (fixed by the reference setup_inputs)
#define MDIM 8192
#define KDIM 2048
#define NDIM 2048
#define QBLK 128
#define KB   (KDIM / QBLK)   // 16
#define NB   (NDIM / QBLK)   // 16

typedef float floatx4 __attribute__((ext_vector_type(4)));
typedef int   int4v   __attribute__((ext_vector_type(4)));
typedef int   int8v   __attribute__((ext_vector_type(8)));

#define AS1 __attribute__((address_space(1)))
#define AS3 __attribute__((address_space(3)))

// ---------------------------------------------------------------------------
// fp8 e4m3fn helpers (software, bit-exact) — used by cold paths + check
// ---------------------------------------------------------------------------
__device__ inline float e4m3_rne(float q) {     // RNE to fp8 grid, |q| <= 448
    float aq = fabsf(q);
    float r;
    if (aq < 0.015625f) {                        // subnormal: grid 2^-9
        r = rintf(aq * 512.0f) * 0.001953125f;
    } else {
        unsigned u = __float_as_uint(aq);
        unsigned rem = u & 0xFFFFFu;
        unsigned base = u & ~0xFFFFFu;
        unsigned inc = (rem > 0x80000u || (rem == 0x80000u && (u & 0x100000u))) ? 0x100000u : 0u;
        r = __uint_as_float(base + inc);
    }
    return q < 0.0f ? -r : r;
}

__device__ inline unsigned e4m3_encode(float r) {  // r exactly on fp8 grid
    unsigned u = __float_as_uint(r);
    unsigned s = (u >> 24) & 0x80u;
    float a = fabsf(r);
    if (a < 0.015625f) return s | (unsigned)(a * 512.0f + 0.25f);
    unsigned e = ((u >> 23) & 0xFFu) - 120u;       // 1..15
    unsigned m = (u >> 20) & 7u;
    return s | (e << 3) | m;
}

__device__ inline float e4m3_decode(unsigned b) {
    unsigned s = b >> 7, e = (b >> 3) & 0xFu, m = b & 7u;
    float v;
    if (e == 0) v = (float)m * 0.001953125f;
    else        v = __uint_as_float((e + 120u) << 23) * (float)(8 + m) * 0.125f;
    return s ? -v : v;
}

__device__ inline int is_expbyte(unsigned b) {   // plausible f32/bf16 hi byte for fp8-exact value
    unsigned e = b & 0x7Fu;
    return (e >= 0x3Bu && e <= 0x43u) || e == 0x00u;
}

// ---------------------------------------------------------------------------
// Workspace layout
//   xq  [M][K]  fp8 bytes            @ 0        (16 MB)
//   wq8 [N][K]  fp8 bytes            @ 16 MB    (4 MB)
//   xs  [M][KB] f32 act scales       @ 20 MB    (512 KB)
//   flag int                         @ 20.5 MB
// ---------------------------------------------------------------------------
#define XQ_OFF  0
#define WQ_OFF  ((size_t)MDIM * KDIM)
#define XS_OFF  (WQ_OFF + (size_t)NDIM * KDIM)
#define FL_OFF  (XS_OFF + (size_t)MDIM * KB * 4)

#define QXB ((MDIM * KB) / 8)          // 16384 act-quant blocks (8 qblocks each)
#define DWB ((NDIM * KDIM / 8) / 256)  // 2048 weight blocks

// ---------------------------------------------------------------------------
// Prep (round-1 best-measured form): act quant (32-lane group per (1,128)
// block, 4 elems/lane) -> fp8 bytes + scales via HW v_cvt_pk_fp8_f32
// (bit-identical RNE from exact IEEE division); weight -> fp8 bytes
// (delivery format classified per wave via ballot).
// ---------------------------------------------------------------------------
__global__ __launch_bounds__(256) void prep_kernel(const float* __restrict__ x,
                                                   const void* __restrict__ wq,
                                                   unsigned char* __restrict__ xq,
                                                   unsigned char* __restrict__ wq8,
                                                   float* __restrict__ xs,
                                                   int* __restrict__ flag) {
    const int tid = threadIdx.x;
    if (blockIdx.x == 0 && tid == 0) *flag = 0;

    if (blockIdx.x < QXB) {
        // ---- activation quant: one 32-lane group per (1,128) block ----
        const int g = tid >> 5;
        const int l = tid & 31;
        const size_t bi = (size_t)blockIdx.x * 8 + g;    // = m*KB + kb
        const size_t base = bi << 7;

        const float4 v = *(const float4*)(x + base + (size_t)l * 4);
        float a = fmaxf(fmaxf(fabsf(v.x), fabsf(v.y)), fmaxf(fabsf(v.z), fabsf(v.w)));
        a = fmaxf(a, __shfl_xor(a, 1));
        a = fmaxf(a, __shfl_xor(a, 2));
        a = fmaxf(a, __shfl_xor(a, 4));
        a = fmaxf(a, __shfl_xor(a, 8));
        a = fmaxf(a, __shfl_xor(a, 16));

        const float scale = fmaxf(a, 1e-12f) / 448.0f;
        if (l == 0) xs[bi] = scale;

        // exact IEEE divisions (same as reference), HW RNE pack to fp8
        const float q0 = v.x / scale, q1 = v.y / scale;
        const float q2 = v.z / scale, q3 = v.w / scale;
        int w = __builtin_amdgcn_cvt_pk_fp8_f32(q0, q1, 0, false);   // bits [15:0]
        w = __builtin_amdgcn_cvt_pk_fp8_f32(q2, q3, w, true);        // bits [31:16]
        *(unsigned*)(xq + base + (size_t)l * 4) = (unsigned)w;
    } else {
        // ---- weight repack to fp8 bytes ----
        const int lane = tid & 63;
        const unsigned pw = ((const unsigned*)wq)[lane];
        const unsigned long long m3 = __ballot(is_expbyte((pw >> 24) & 0xFFu));
        const unsigned long long m1 = __ballot(((pw >> 8) & 0xFFu) == 0u);
        const int f = (__popcll(m3) >= 56) ? ((__popcll(m1) >= 56) ? 2 : 1) : 0;

        const size_t idx = (size_t)(blockIdx.x - QXB) * 256 + tid;
        const size_t off = idx * 8;

        unsigned lo, hi;
        if (f == 2) {              // float32 upcast delivery
            const float4* p = (const float4*)((const float*)wq + off);
            const float4 a = p[0], b = p[1];
            lo = e4m3_encode(a.x) | (e4m3_encode(a.y) << 8) | (e4m3_encode(a.z) << 16) | (e4m3_encode(a.w) << 24);
            hi = e4m3_encode(b.x) | (e4m3_encode(b.y) << 8) | (e4m3_encode(b.z) << 16) | (e4m3_encode(b.w) << 24);
        } else if (f == 1) {       // bf16 upcast delivery
            const ushort4 h0 = *(const ushort4*)((const unsigned short*)wq + off);
            const ushort4 h1 = *(((const ushort4*)((const unsigned short*)wq + off)) + 1);
            lo = e4m3_encode(__uint_as_float((unsigned)h0.x << 16))
               | (e4m3_encode(__uint_as_float((unsigned)h0.y << 16)) << 8)
               | (e4m3_encode(__uint_as_float((unsigned)h0.z << 16)) << 16)
               | (e4m3_encode(__uint_as_float((unsigned)h0.w << 16)) << 24);
            hi = e4m3_encode(__uint_as_float((unsigned)h1.x << 16))
               | (e4m3_encode(__uint_as_float((unsigned)h1.y << 16)) << 8)
               | (e4m3_encode(__uint_as_float((unsigned)h1.z << 16)) << 16)
               | (e4m3_encode(__uint_as_float((unsigned)h1.w << 16)) << 24);
        } else {                   // already raw fp8 bytes
            const uint2 d = *(const uint2*)((const unsigned char*)wq + off);
            lo = d.x; hi = d.y;
        }
        *(uint2*)(wq8 + off) = make_uint2(lo, hi);
    }
}

// ---------------------------------------------------------------------------
// Primary GEMM: round-0 verified kernel (128x128 tile, 4 waves 2x2 of 64x64,
// MX fp8 K=128, single-buffer 2-barrier m148 structure, XOR-swizzled 16B
// chunks) with EXACTLY three deltas from the 68.4 µs baseline:
//   1. __launch_bounds__(256, 3): 3 blocks/CU (LDS 41 KB x3 = 123 KB fits;
//      VGPR cap 170 >> measured 104 -> no spill). m148's occupancy: the
//      2-barrier drain is hidden by other resident blocks' compute.
//   2. Act scales staged ONCE into LDS transposed (sxs) + weight scales
//      (swk): removes 16 uncoalesced per-lane global loads per thread per
//      K-tile (~2k cycles/CU/K-tile of scattered L2 traffic).
//   3. Nothing else. Staging/FRAG/MFMA/epilogue byte-identical to round 0.
// ---------------------------------------------------------------------------
__global__ __launch_bounds__(256, 3) void gemm_mx_kernel(const unsigned char* __restrict__ Aq,
                                                         const unsigned char* __restrict__ Bq,
                                                         const float* __restrict__ xs,
                                                         const float* __restrict__ wsc,
                                                         float* __restrict__ C) {
    __shared__ unsigned char sA[128 * 128];   // 16 KB
    __shared__ unsigned char sB[128 * 128];   // 16 KB
    __shared__ float sxs[KB][128];            // 8 KB transposed act scales
    __shared__ float swk[KB];                 // weight scales for this n-tile

    const int tid  = threadIdx.x;
    const int wave = tid >> 6;
    const int lane = tid & 63;
    const int lrow = lane & 15;
    const int lk   = lane >> 4;          // k-group (32 bytes each)
    const int lk4  = lk * 4;
    const int wm   = (wave & 1) * 64;
    const int wn   = (wave >> 1) * 64;
    const int m0   = blockIdx.y * 128;
    const int n0   = blockIdx.x * 128;
    const int nb   = n0 >> 7;

    // staging: thread t -> LDS bytes [t*16 + it*4096): row = t/8 + it*32,
    // physical chunk = t&7 holding logical chunk (t&7)^(row&7).
    const int srow = tid >> 3;
    const int gck  = (tid & 7) ^ (srow & 7);
    const unsigned char* agp = Aq + (size_t)(m0 + srow) * KDIM + gck * 16;
    const unsigned char* bgp = Bq + (size_t)(n0 + srow) * KDIM + gck * 16;

    // one-time scale staging (ordered by the loop's first __syncthreads)
    if (tid < 128) {
        const float4* xp = (const float4*)(xs + (size_t)(m0 + tid) * KB);
#pragma unroll
        for (int q = 0; q < 4; ++q) {
            const float4 v = xp[q];
            sxs[q * 4 + 0][tid] = v.x;
            sxs[q * 4 + 1][tid] = v.y;
            sxs[q * 4 + 2][tid] = v.z;
            sxs[q * 4 + 3][tid] = v.w;
        }
    }
    if (tid < KB) swk[tid] = wsc[nb * KB + tid];

    floatx4 acc[4][4] = {};
    const floatx4 zero = {0.f, 0.f, 0.f, 0.f};

    for (int kb = 0; kb < KB; ++kb) {            // 16 iterations, 128 K each
        const size_t koff = (size_t)kb * QBLK;   // byte offset in a row
        __syncthreads();
#pragma unroll
        for (int it = 0; it < 4; ++it)
            __builtin_amdgcn_global_load_lds(
                (const AS1 void*)(agp + (size_t)(it * 32) * KDIM + koff),
                (AS3 void*)(sA + tid * 16 + it * 4096), 16, 0, 0);
#pragma unroll
        for (int it = 0; it < 4; ++it)
            __builtin_amdgcn_global_load_lds(
                (const AS1 void*)(bgp + (size_t)(it * 32) * KDIM + koff),
                (AS3 void*)(sB + tid * 16 + it * 4096), 16, 0, 0);
        __syncthreads();

        // fragments: logical bytes [lk*32, lk*32+32) of each row
        int8v af[4], bf[4];
#pragma unroll
        for (int i = 0; i < 4; ++i) {
            const int Ra = wm + i * 16 + lrow;
            const int c0 = (lk * 2) ^ (Ra & 7);
            const int c1 = (lk * 2 + 1) ^ (Ra & 7);
            int4v alo = *(const int4v*)(sA + Ra * 128 + c0 * 16);
            int4v ahi = *(const int4v*)(sA + Ra * 128 + c1 * 16);
            af[i] = __builtin_shufflevector(alo, ahi, 0, 1, 2, 3, 4, 5, 6, 7);
            const int Rb = wn + i * 16 + lrow;
            const int d0 = (lk * 2) ^ (Rb & 7);
            const int d1 = (lk * 2 + 1) ^ (Rb & 7);
            int4v blo = *(const int4v*)(sB + Rb * 128 + d0 * 16);
            int4v bhi = *(const int4v*)(sB + Rb * 128 + d1 * 16);
            bf[i] = __builtin_shufflevector(blo, bhi, 0, 1, 2, 3, 4, 5, 6, 7);
        }

        // combined per-row scales for this k-block (C/D row = lk*4 + r),
        // now broadcast LDS reads instead of 16 scattered global loads
        const float wsk = swk[kb];
        float cs[4][4];
#pragma unroll
        for (int i = 0; i < 4; ++i) {
            const floatx4 cv = *(const floatx4*)&sxs[kb][wm + i * 16 + lk4];
            cs[i][0] = cv[0] * wsk;
            cs[i][1] = cv[1] * wsk;
            cs[i][2] = cv[2] * wsk;
            cs[i][3] = cv[3] * wsk;
        }

#pragma unroll
        for (int i = 0; i < 4; ++i)
#pragma unroll
            for (int j = 0; j < 4; ++j) {
                floatx4 blk = __builtin_amdgcn_mfma_scale_f32_16x16x128_f8f6f4(
                    af[i], bf[j], zero, 0, 0, 0, 0x7F7F7F7F, 0, 0x7F7F7F7F);
#pragma unroll
                for (int r = 0; r < 4; ++r)
                    acc[i][j][r] += cs[i][r] * blk[r];
            }
    }

    // Epilogue: col = lane&15, row = lk*4 + r.
#pragma unroll
    for (int i = 0; i < 4; ++i) {
        const int row0 = m0 + wm + i * 16 + lk4;
#pragma unroll
        for (int r = 0; r < 4; ++r) {
            float* cp = C + (size_t)(row0 + r) * NDIM + n0 + wn + lrow;
#pragma unroll
            for (int j = 0; j < 4; ++j)
                cp[j * 16] = acc[i][j][r];
        }
    }
}

// ---------------------------------------------------------------------------
// Check: recompute 64 sampled outputs exactly from the quantized bytes; set
// flag if the MX GEMM result deviates (NaN-safe compare).
// ---------------------------------------------------------------------------
__global__ __launch_bounds__(256) void check_kernel(const unsigned char* __restrict__ xq,
                                                    const unsigned char* __restrict__ wq8,
                                                    const float* __restrict__ xs,
                                                    const float* __restrict__ wsc,
                                                    const float* __restrict__ y,
                                                    int* __restrict__ flag) {
    const int s = blockIdx.x;
    const int m = (s * 1237 + 11) & (MDIM - 1);
    const int n = (s * 389 + 7) & (NDIM - 1);
    const int tid = threadIdx.x;
    const int k0 = tid * 8;
    const int kb = k0 >> 7;

    const unsigned char* xp = xq + (size_t)m * KDIM + k0;
    const unsigned char* wp = wq8 + (size_t)n * KDIM + k0;
    float dot = 0.f;
#pragma unroll
    for (int i = 0; i < 8; ++i)
        dot += e4m3_decode(xp[i]) * e4m3_decode(wp[i]);
    float part = dot * xs[m * KB + kb] * wsc[(n >> 7) * KB + kb];

#pragma unroll
    for (int o = 32; o > 0; o >>= 1) part += __shfl_down(part, o);
    __shared__ float wsum[4];
    if ((tid & 63) == 0) wsum[tid >> 6] = part;
    __syncthreads();
    if (tid == 0) {
        const float tot = wsum[0] + wsum[1] + wsum[2] + wsum[3];
        const float d = tot - y[(size_t)m * NDIM + n];
        if (!(fabsf(d) <= 0.05f)) atomicOr(flag, 1);
    }
}

// ---------------------------------------------------------------------------
// Fallback GEMM (flag-guarded): non-scaled mfma_f32_16x16x32_fp8_fp8 (m145-
// verified k-geometry) + identical VALU scale fixup. Only runs if the MX
// layout check failed. Unchanged from the verified kernel.
// ---------------------------------------------------------------------------
__global__ __launch_bounds__(256, 2) void gemm_fb_kernel(const unsigned char* __restrict__ Aq,
                                                         const unsigned char* __restrict__ Bq,
                                                         const float* __restrict__ xs,
                                                         const float* __restrict__ wsc,
                                                         float* __restrict__ C,
                                                         const int* __restrict__ flag) {
    if (*flag == 0) return;

    __shared__ unsigned char sA[128 * 128];
    __shared__ unsigned char sB[128 * 128];

    const int tid  = threadIdx.x;
    const int wave = tid >> 6;
    const int lane = tid & 63;
    const int lrow = lane & 15;
    const int lk   = lane >> 4;
    const int wm   = (wave & 1) * 64;
    const int wn   = (wave >> 1) * 64;
    const int m0   = blockIdx.y * 128;
    const int n0   = blockIdx.x * 128;
    const int nb   = n0 >> 7;

    const int srow = tid >> 3;
    const int gck  = (tid & 7) ^ (srow & 7);
    const unsigned char* agp = Aq + (size_t)(m0 + srow) * KDIM + gck * 16;
    const unsigned char* bgp = Bq + (size_t)(n0 + srow) * KDIM + gck * 16;

    floatx4 acc[4][4] = {};

    for (int kb = 0; kb < KB; ++kb) {
        const size_t koff = (size_t)kb * QBLK;
        __syncthreads();
#pragma unroll
        for (int it = 0; it < 4; ++it)
            __builtin_amdgcn_global_load_lds(
                (const AS1 void*)(agp + (size_t)(it * 32) * KDIM + koff),
                (AS3 void*)(sA + tid * 16 + it * 4096), 16, 0, 0);
#pragma unroll
        for (int it = 0; it < 4; ++it)
            __builtin_amdgcn_global_load_lds(
                (const AS1 void*)(bgp + (size_t)(it * 32) * KDIM + koff),
                (AS3 void*)(sB + tid * 16 + it * 4096), 16, 0, 0);
        __syncthreads();

        floatx4 blk[4][4] = {};
#pragma unroll
        for (int ks = 0; ks < 4; ++ks) {        // K = 32 per MFMA
            long a8[4], b8[4];
            const int lc = ks * 2 + (lk >> 1);  // logical chunk of this 8B frag
            const int bo = (lk & 1) * 8;        // byte offset within chunk
#pragma unroll
            for (int i = 0; i < 4; ++i) {
                const int Ra = wm + i * 16 + lrow;
                a8[i] = *(const long*)(sA + Ra * 128 + (lc ^ (Ra & 7)) * 16 + bo);
                const int Rb = wn + i * 16 + lrow;
                b8[i] = *(const long*)(sB + Rb * 128 + (lc ^ (Rb & 7)) * 16 + bo);
            }
#pragma unroll
            for (int i = 0; i < 4; ++i)
#pragma unroll
                for (int j = 0; j < 4; ++j)
                    blk[i][j] = __builtin_amdgcn_mfma_f32_16x16x32_fp8_fp8(a8[i], b8[j], blk[i][j], 0, 0, 0);
        }

        const float wsk = wsc[nb * KB + kb];
#pragma unroll
        for (int i = 0; i < 4; ++i) {
            float cs[4];
#pragma unroll
            for (int r = 0; r < 4; ++r)
                cs[r] = xs[(size_t)(m0 + wm + i * 16 + lk * 4 + r) * KB + kb] * wsk;
#pragma unroll
            for (int j = 0; j < 4; ++j)
#pragma unroll
                for (int r = 0; r < 4; ++r)
                    acc[i][j][r] += cs[r] * blk[i][j][r];
        }
    }

#pragma unroll
    for (int i = 0; i < 4; ++i) {
        const int row0 = m0 + wm + i * 16 + lk * 4;
#pragma unroll
        for (int r = 0; r < 4; ++r) {
            float* cp = C + (size_t)(row0 + r) * NDIM + n0 + wn + lrow;
#pragma unroll
            for (int j = 0; j < 4; ++j)
                cp[j * 16] = acc[i][j][r];
        }
    }
}

// ---------------------------------------------------------------------------
extern "C" void kernel_launch(void* const* d_in, const int* in_sizes, int n_in,
                              void* d_out, int out_size, void* d_ws, size_t ws_size,
                              hipStream_t stream) {
    const float* x      = (const float*)d_in[0];
    const void* wq      = d_in[1];
    const float* wscale = (const float*)d_in[2];
    float* y            = (float*)d_out;

    unsigned char* xq  = (unsigned char*)d_ws + XQ_OFF;
    unsigned char* wq8 = (unsigned char*)d_ws + WQ_OFF;
    float* xs          = (float*)((unsigned char*)d_ws + XS_OFF);
    int* flag          = (int*)((unsigned char*)d_ws + FL_OFF);

    prep_kernel<<<QXB + DWB, 256, 0, stream>>>(x, wq, xq, wq8, xs, flag);
    gemm_mx_kernel<<<dim3(NDIM / 128, MDIM / 128), 256, 0, stream>>>(xq, wq8, xs, wscale, y);
    check_kernel<<<64, 256, 0, stream>>>(xq, wq8, xs, wscale, y, flag);
    gemm_fb_kernel<<<dim3(NDIM / 128, MDIM / 128), 256, 0, stream>>>(xq, wq8, xs, wscale, y, flag);
}

// Round 6
// 167.990 us; speedup vs baseline: 4.0576x; 1.0817x over previous
//
#include <hip/hip_runtime.h>
#include <cstdint>
#include <cstddef>

// Problem shape (fixed by the reference setup_inputs)
#define MDIM 8192
#define KDIM 2048
#define NDIM 2048
#define QBLK 128
#define KB   (KDIM / QBLK)   // 16
#define NB   (NDIM / QBLK)   // 16

typedef float floatx4 __attribute__((ext_vector_type(4)));
typedef int   int4v   __attribute__((ext_vector_type(4)));
typedef int   int8v   __attribute__((ext_vector_type(8)));

#define AS1 __attribute__((address_space(1)))
#define AS3 __attribute__((address_space(3)))

// ---------------------------------------------------------------------------
// fp8 e4m3fn helpers (software, bit-exact) — prep weight path
// ---------------------------------------------------------------------------
__device__ inline unsigned e4m3_encode(float r) {  // r exactly on fp8 grid
    unsigned u = __float_as_uint(r);
    unsigned s = (u >> 24) & 0x80u;
    float a = fabsf(r);
    if (a < 0.015625f) return s | (unsigned)(a * 512.0f + 0.25f);
    unsigned e = ((u >> 23) & 0xFFu) - 120u;       // 1..15
    unsigned m = (u >> 20) & 7u;
    return s | (e << 3) | m;
}

__device__ inline int is_expbyte(unsigned b) {   // plausible f32/bf16 hi byte for fp8-exact value
    unsigned e = b & 0x7Fu;
    return (e >= 0x3Bu && e <= 0x43u) || e == 0x00u;
}

// ---------------------------------------------------------------------------
// Workspace layout
//   xq  [M][K]  fp8 bytes            @ 0        (16 MB)
//   wq8 [N][K]  fp8 bytes            @ 16 MB    (4 MB)
//   xs  [M][KB] f32 act scales       @ 20 MB    (512 KB)
// ---------------------------------------------------------------------------
#define XQ_OFF  0
#define WQ_OFF  ((size_t)MDIM * KDIM)
#define XS_OFF  (WQ_OFF + (size_t)NDIM * KDIM)

#define QXB ((MDIM * KB) / 16)         // 8192 act-quant blocks (16 qblocks each)
#define DWB ((NDIM * KDIM / 8) / 256)  // 2048 weight blocks

// ---------------------------------------------------------------------------
// Prep (round-1 best-measured form): act quant (8 elems/lane, 16 lanes per
// (1,128) block) -> fp8 bytes + scales via HW v_cvt_pk_fp8_f32 (bit-identical
// RNE from exact IEEE division); weight -> fp8 bytes (delivery format
// classified per wave via ballot).
// ---------------------------------------------------------------------------
__global__ __launch_bounds__(256) void prep_kernel(const float* __restrict__ x,
                                                   const void* __restrict__ wq,
                                                   unsigned char* __restrict__ xq,
                                                   unsigned char* __restrict__ wq8,
                                                   float* __restrict__ xs) {
    const int tid = threadIdx.x;

    if (blockIdx.x < QXB) {
        // ---- activation quant: one 16-lane group per (1,128) block ----
        const int g = tid >> 4;
        const int l = tid & 15;
        const size_t bi = (size_t)blockIdx.x * 16 + g;   // = m*KB + kb
        const size_t base = bi << 7;

        const float4* xp = (const float4*)(x + base + (size_t)l * 8);
        const float4 v0 = xp[0], v1 = xp[1];
        float a = fmaxf(fmaxf(fmaxf(fabsf(v0.x), fabsf(v0.y)), fmaxf(fabsf(v0.z), fabsf(v0.w))),
                        fmaxf(fmaxf(fabsf(v1.x), fabsf(v1.y)), fmaxf(fabsf(v1.z), fabsf(v1.w))));
        a = fmaxf(a, __shfl_xor(a, 1));
        a = fmaxf(a, __shfl_xor(a, 2));
        a = fmaxf(a, __shfl_xor(a, 4));
        a = fmaxf(a, __shfl_xor(a, 8));

        const float scale = fmaxf(a, 1e-12f) / 448.0f;
        if (l == 0) xs[bi] = scale;

        // exact IEEE divisions (same as reference), HW RNE pack to fp8
        const float q0 = v0.x / scale, q1 = v0.y / scale, q2 = v0.z / scale, q3 = v0.w / scale;
        const float q4 = v1.x / scale, q5 = v1.y / scale, q6 = v1.z / scale, q7 = v1.w / scale;
        int w0 = __builtin_amdgcn_cvt_pk_fp8_f32(q0, q1, 0, false);
        w0 = __builtin_amdgcn_cvt_pk_fp8_f32(q2, q3, w0, true);
        int w1 = __builtin_amdgcn_cvt_pk_fp8_f32(q4, q5, 0, false);
        w1 = __builtin_amdgcn_cvt_pk_fp8_f32(q6, q7, w1, true);
        *(uint2*)(xq + base + (size_t)l * 8) = make_uint2((unsigned)w0, (unsigned)w1);
    } else {
        // ---- weight repack to fp8 bytes ----
        const int lane = tid & 63;
        const unsigned pw = ((const unsigned*)wq)[lane];
        const unsigned long long m3 = __ballot(is_expbyte((pw >> 24) & 0xFFu));
        const unsigned long long m1 = __ballot(((pw >> 8) & 0xFFu) == 0u);
        const int f = (__popcll(m3) >= 56) ? ((__popcll(m1) >= 56) ? 2 : 1) : 0;

        const size_t idx = (size_t)(blockIdx.x - QXB) * 256 + tid;
        const size_t off = idx * 8;

        unsigned lo, hi;
        if (f == 2) {              // float32 upcast delivery (values exactly on fp8 grid)
            const float4* p = (const float4*)((const float*)wq + off);
            const float4 a = p[0], b = p[1];
            lo = e4m3_encode(a.x) | (e4m3_encode(a.y) << 8) | (e4m3_encode(a.z) << 16) | (e4m3_encode(a.w) << 24);
            hi = e4m3_encode(b.x) | (e4m3_encode(b.y) << 8) | (e4m3_encode(b.z) << 16) | (e4m3_encode(b.w) << 24);
        } else if (f == 1) {       // bf16 upcast delivery
            const ushort4 h0 = *(const ushort4*)((const unsigned short*)wq + off);
            const ushort4 h1 = *(((const ushort4*)((const unsigned short*)wq + off)) + 1);
            lo = e4m3_encode(__uint_as_float((unsigned)h0.x << 16))
               | (e4m3_encode(__uint_as_float((unsigned)h0.y << 16)) << 8)
               | (e4m3_encode(__uint_as_float((unsigned)h0.z << 16)) << 16)
               | (e4m3_encode(__uint_as_float((unsigned)h0.w << 16)) << 24);
            hi = e4m3_encode(__uint_as_float((unsigned)h1.x << 16))
               | (e4m3_encode(__uint_as_float((unsigned)h1.y << 16)) << 8)
               | (e4m3_encode(__uint_as_float((unsigned)h1.z << 16)) << 16)
               | (e4m3_encode(__uint_as_float((unsigned)h1.w << 16)) << 24);
        } else {                   // already raw fp8 bytes
            const uint2 d = *(const uint2*)((const unsigned char*)wq + off);
            lo = d.x; hi = d.y;
        }
        *(uint2*)(wq8 + off) = make_uint2(lo, hi);
    }
}

// ---------------------------------------------------------------------------
// Primary GEMM: 128x128 tile, 4 waves (2x2 of 64x64), MX fp8 K=128 per MFMA,
// single-buffer 2-barrier structure, XOR-swizzled 16B chunks — the verified
// round-0 body with three occupancy deltas:
//   1. __launch_bounds__(256, 4): caps TOTAL regs (arch+acc) at 128. The m69
//      HW step (waves/CU halves at 64/128/256 total regs) means 148 regs ->
//      8 waves/CU no matter what launch_bounds asks (R5 measured); <=128 ->
//      16-wave bucket, LDS then admits 3 blocks = 12 waves/CU.
//   2. A-fragment read moved INSIDE the i-loop: af liveness 32->8 regs
//      (bf[4] kept). Same LDS traffic (8 x ds_read_b128 per wave per tile).
//   3. wsc premultiplied into sxs at fill (drops swk + per-tile mul);
//      LDS = 16K+16K+8K = 40960 B exactly.
// Spill tripwire: WRITE_SIZE must stay ~65.5e3 KB (R3/R4's 1e6 = scratch).
// ---------------------------------------------------------------------------
__global__ __launch_bounds__(256, 4) void gemm_mx_kernel(const unsigned char* __restrict__ Aq,
                                                         const unsigned char* __restrict__ Bq,
                                                         const float* __restrict__ xs,
                                                         const float* __restrict__ wsc,
                                                         float* __restrict__ C) {
    __shared__ unsigned char sA[128 * 128];   // 16 KB
    __shared__ unsigned char sB[128 * 128];   // 16 KB
    __shared__ float sxs[KB][128];            // 8 KB combined scales xs*wsk

    const int tid  = threadIdx.x;
    const int wave = tid >> 6;
    const int lane = tid & 63;
    const int lrow = lane & 15;
    const int lk   = lane >> 4;          // k-group (32 bytes each)
    const int lk4  = lk * 4;
    const int wm   = (wave & 1) * 64;
    const int wn   = (wave >> 1) * 64;
    const int m0   = blockIdx.y * 128;
    const int n0   = blockIdx.x * 128;
    const int nb   = n0 >> 7;

    // staging: thread t -> LDS bytes [t*16 + it*4096): row = t/8 + it*32,
    // physical chunk = t&7 holding logical chunk (t&7)^(row&7).
    const int srow = tid >> 3;
    const int gck  = (tid & 7) ^ (srow & 7);
    const unsigned char* agp = Aq + (size_t)(m0 + srow) * KDIM + gck * 16;
    const unsigned char* bgp = Bq + (size_t)(n0 + srow) * KDIM + gck * 16;

    // one-time combined-scale staging (ordered by the loop's first barrier)
    if (tid < 128) {
        const float4* xp = (const float4*)(xs + (size_t)(m0 + tid) * KB);
        const float* wp = wsc + nb * KB;
#pragma unroll
        for (int q = 0; q < 4; ++q) {
            const float4 v = xp[q];
            sxs[q * 4 + 0][tid] = v.x * wp[q * 4 + 0];
            sxs[q * 4 + 1][tid] = v.y * wp[q * 4 + 1];
            sxs[q * 4 + 2][tid] = v.z * wp[q * 4 + 2];
            sxs[q * 4 + 3][tid] = v.w * wp[q * 4 + 3];
        }
    }

    floatx4 acc[4][4] = {};
    const floatx4 zero = {0.f, 0.f, 0.f, 0.f};

    for (int kb = 0; kb < KB; ++kb) {            // 16 iterations, 128 K each
        const size_t koff = (size_t)kb * QBLK;   // byte offset in a row
        __syncthreads();
#pragma unroll
        for (int it = 0; it < 4; ++it)
            __builtin_amdgcn_global_load_lds(
                (const AS1 void*)(agp + (size_t)(it * 32) * KDIM + koff),
                (AS3 void*)(sA + tid * 16 + it * 4096), 16, 0, 0);
#pragma unroll
        for (int it = 0; it < 4; ++it)
            __builtin_amdgcn_global_load_lds(
                (const AS1 void*)(bgp + (size_t)(it * 32) * KDIM + koff),
                (AS3 void*)(sB + tid * 16 + it * 4096), 16, 0, 0);
        __syncthreads();

        // B fragments held (32 regs); A fragment read per-i (8 regs live)
        int8v bf[4];
#pragma unroll
        for (int j = 0; j < 4; ++j) {
            const int Rb = wn + j * 16 + lrow;
            const int d0 = (lk * 2) ^ (Rb & 7);
            const int d1 = (lk * 2 + 1) ^ (Rb & 7);
            int4v blo = *(const int4v*)(sB + Rb * 128 + d0 * 16);
            int4v bhi = *(const int4v*)(sB + Rb * 128 + d1 * 16);
            bf[j] = __builtin_shufflevector(blo, bhi, 0, 1, 2, 3, 4, 5, 6, 7);
        }

#pragma unroll
        for (int i = 0; i < 4; ++i) {
            const int Ra = wm + i * 16 + lrow;
            const int c0 = (lk * 2) ^ (Ra & 7);
            const int c1 = (lk * 2 + 1) ^ (Ra & 7);
            int4v alo = *(const int4v*)(sA + Ra * 128 + c0 * 16);
            int4v ahi = *(const int4v*)(sA + Ra * 128 + c1 * 16);
            int8v af = __builtin_shufflevector(alo, ahi, 0, 1, 2, 3, 4, 5, 6, 7);

            // combined per-row scales for this k-block (C/D row = lk*4 + r)
            const floatx4 cs = *(const floatx4*)&sxs[kb][wm + i * 16 + lk4];

#pragma unroll
            for (int j = 0; j < 4; ++j) {
                floatx4 blk = __builtin_amdgcn_mfma_scale_f32_16x16x128_f8f6f4(
                    af, bf[j], zero, 0, 0, 0, 0x7F7F7F7F, 0, 0x7F7F7F7F);
#pragma unroll
                for (int r = 0; r < 4; ++r)
                    acc[i][j][r] += cs[r] * blk[r];
            }
        }
    }

    // Epilogue: col = lane&15, row = lk*4 + r.
#pragma unroll
    for (int i = 0; i < 4; ++i) {
        const int row0 = m0 + wm + i * 16 + lk4;
#pragma unroll
        for (int r = 0; r < 4; ++r) {
            float* cp = C + (size_t)(row0 + r) * NDIM + n0 + wn + lrow;
#pragma unroll
            for (int j = 0; j < 4; ++j)
                cp[j * 16] = acc[i][j][r];
        }
    }
}

// ---------------------------------------------------------------------------
extern "C" void kernel_launch(void* const* d_in, const int* in_sizes, int n_in,
                              void* d_out, int out_size, void* d_ws, size_t ws_size,
                              hipStream_t stream) {
    const float* x      = (const float*)d_in[0];
    const void* wq      = d_in[1];
    const float* wscale = (const float*)d_in[2];
    float* y            = (float*)d_out;

    unsigned char* xq  = (unsigned char*)d_ws + XQ_OFF;
    unsigned char* wq8 = (unsigned char*)d_ws + WQ_OFF;
    float* xs          = (float*)((unsigned char*)d_ws + XS_OFF);

    prep_kernel<<<QXB + DWB, 256, 0, stream>>>(x, wq, xq, wq8, xs);
    gemm_mx_kernel<<<dim3(NDIM / 128, MDIM / 128), 256, 0, stream>>>(xq, wq8, xs, wscale, y);
}